// Round 5
// baseline (183.943 us; speedup 1.0000x reference)
//
#include <hip/hip_runtime.h>
#include <hip/hip_bf16.h>
#include <stdint.h>

#define T_TOKENS 8192
#define F_DIM    2048
#define E_EXP    16
#define R_RANK   16
#define O_DIM    2048
#define KDIM     (E_EXP * R_RANK)   // 256

typedef short v8s __attribute__((ext_vector_type(8)));
typedef float v4f __attribute__((ext_vector_type(4)));

#define AS1 __attribute__((address_space(1)))
#define AS3 __attribute__((address_space(3)))

__device__ __forceinline__ uint16_t f2bf(float f) {
  uint32_t u = __builtin_bit_cast(uint32_t, f);
  u += 0x7fffu + ((u >> 16) & 1u);   // round-to-nearest-even
  return (uint16_t)(u >> 16);
}

// async global->LDS, 16B per lane; LDS dest = wave-uniform base + lane*16
__device__ __forceinline__ void g2lds16(const void* g, void* l) {
  __builtin_amdgcn_global_load_lds((const AS1 void*)g, (AS3 void*)l, 16, 0, 0);
}

// ---------------------------------------------------------------------------
// K0: cast A_stack -> bf16; gather-transpose B_stack (E,O,R) -> Bb (O,K) bf16.
// (R0-exact)
// ---------------------------------------------------------------------------
__global__ __launch_bounds__(256) void prep_weights(
    const float* __restrict__ A, const float* __restrict__ Bst,
    uint16_t* __restrict__ Ab, uint16_t* __restrict__ Bb) {
  int idx = blockIdx.x * 256 + threadIdx.x;
  if (idx < KDIM * F_DIM) {
    Ab[idx] = f2bf(A[idx]);
  }
  if (idx < O_DIM * KDIM) {
    int k = idx & (KDIM - 1);
    int o = idx >> 8;
    int e = k >> 4, r = k & 15;
    Bb[idx] = f2bf(Bst[((size_t)e * O_DIM + o) * R_RANK + r]);
  }
}

// ---------------------------------------------------------------------------
// K1: route_stream (R4-exact, throughput shape): 2048 blocks (8/CU),
// 32 tokens x 256 cols per block, 1 thread = 1 token x 32 cols.
// Partials layout: float4 partials4[(c*4+e4)*8192 + t].
// ---------------------------------------------------------------------------
__global__ __launch_bounds__(256) void route_stream(
    const float* __restrict__ x, const float* __restrict__ P,
    uint16_t* __restrict__ xb, float4* __restrict__ partials4) {
  __shared__ float ps[16 * 256];   // 16 KB, linear (g2lds dest)
  const int tid = threadIdx.x;
  const int c   = blockIdx.x;      // 0..7  (256-col chunk)
  const int by  = blockIdx.y;      // 0..255 (32-token block)
  const int f0  = c * 256;

  #pragma unroll
  for (int p = 0; p < 4; ++p) {
    const int G = p * 256 + tid;                  // 0..1023
    g2lds16(&P[(size_t)(G >> 6) * F_DIM + f0 + (G & 63) * 4],
            (char*)ps + (p * 256 + (tid >> 6) * 64) * 16);
  }
  __syncthreads();

  const int sub = tid & 7;         // 32-col slice: cols {sub*4 + k*32}
  const int tg  = tid >> 3;        // 0..31 token within block
  const int row = by * 32 + tg;
  const float* xr = x  + (size_t)row * F_DIM + f0;
  uint16_t*    xw = xb + (size_t)row * F_DIM + f0;

  float a[16];
  #pragma unroll
  for (int e = 0; e < 16; ++e) a[e] = 0.f;

  float4 v[8];
  #pragma unroll
  for (int k = 0; k < 8; ++k)
    v[k] = *(const float4*)&xr[sub * 4 + k * 32];

  #pragma unroll
  for (int k = 0; k < 8; ++k) {
    uint2 pk;
    pk.x = (uint32_t)f2bf(v[k].x) | ((uint32_t)f2bf(v[k].y) << 16);
    pk.y = (uint32_t)f2bf(v[k].z) | ((uint32_t)f2bf(v[k].w) << 16);
    *(uint2*)&xw[sub * 4 + k * 32] = pk;
  }

  #pragma unroll
  for (int k = 0; k < 8; ++k) {
    const int col = sub * 4 + k * 32;
    #pragma unroll
    for (int e = 0; e < 16; ++e) {
      float4 pv = *(float4*)&ps[e * 256 + col];
      a[e] += v[k].x * pv.x; a[e] += v[k].y * pv.y;
      a[e] += v[k].z * pv.z; a[e] += v[k].w * pv.w;
    }
  }

  #pragma unroll
  for (int m = 1; m <= 4; m <<= 1) {
    #pragma unroll
    for (int e = 0; e < 16; ++e)
      a[e] += __shfl_xor(a[e], m, 64);
  }

  if (sub < 4) {
    partials4[((size_t)c * 4 + sub) * T_TOKENS + row] =
        make_float4(a[sub * 4], a[sub * 4 + 1], a[sub * 4 + 2], a[sub * 4 + 3]);
  }
}

// ---------------------------------------------------------------------------
// K2: gemm_xa v2 — N-FULL tiles: 256 blocks x 512 threads, 32 tokens x 256
// cols each. xb read ONCE from HBM (was 4x), staged via g2lds ping-pong
// (8 KB x 2, XOR-swizzled); A fragments per-lane DIRECT from L2-resident Ab
// (no LDS, no barrier coupling; numerics validated in R3's fused_xa).
// 8 waves (2/SIMD): wave = 32 rows x 32 cols, acc[2][2], 4 MFMA/K-step.
// Routing prologue (tid<32): R0-exact fp64 cross-chunk sum + topk + softmax.
// ---------------------------------------------------------------------------
__global__ __launch_bounds__(512) void gemm_xa(
    const uint16_t* __restrict__ xb, const uint16_t* __restrict__ Ab,
    const float4* __restrict__ partials4, const float* __restrict__ scaling,
    const int* __restrict__ topk, uint16_t* __restrict__ wb) {
  __shared__ uint16_t S[8448];          // 16.5 KB: X ping/pong, reused as tile
  __shared__ float coeffL[32 * 17];
  uint16_t* X0 = S;                     // 32 rows x 16 granules x 16B = 8 KB
  uint16_t* X1 = S + 4096;
  const int tid  = threadIdx.x;
  const int m0   = blockIdx.x * 32;     // 256 blocks
  const int lane = tid & 63;
  const int wid  = tid >> 6;            // 0..7
  const int quad = lane >> 4;
  const int cl   = lane & 15;

  // ---- routing prologue: tokens m0..m0+31 (fp64, R0-exact numerics) ----
  if (tid < 32) {
    const int t = m0 + tid;
    double s[16];
    #pragma unroll
    for (int e = 0; e < 16; ++e) s[e] = 0.0;
    for (int c = 0; c < 8; ++c) {
      #pragma unroll
      for (int e4 = 0; e4 < 4; ++e4) {
        float4 p = partials4[((size_t)c * 4 + e4) * T_TOKENS + t];
        s[e4 * 4]     += (double)p.x;
        s[e4 * 4 + 1] += (double)p.y;
        s[e4 * 4 + 2] += (double)p.z;
        s[e4 * 4 + 3] += (double)p.w;
      }
    }
    double v[16];
    #pragma unroll
    for (int e = 0; e < 16; ++e) v[e] = fabs(s[e]);
    int k = topk[0];
    if (k > 16) k = 16;
    if (k < 1)  k = 1;
    unsigned mask = 0;
    double mx = 0.0;
    float ssum = 0.f;
    for (int i = 0; i < k; ++i) {
      double bv = -1.0; int bj = 0;
      #pragma unroll
      for (int j = 0; j < 16; ++j) {
        bool ok = !((mask >> j) & 1u) && (v[j] > bv);
        bv = ok ? v[j] : bv;
        bj = ok ? j  : bj;
      }
      mask |= 1u << bj;
      if (i == 0) mx = bv;
      ssum += expf((float)(bv - mx));
    }
    const float sc = scaling[0];
    #pragma unroll
    for (int j = 0; j < 16; ++j)
      coeffL[tid * 17 + j] = ((mask >> j) & 1u)
          ? expf((float)(v[j] - mx)) / ssum * sc : 0.f;
  }

  // ---- staging setup: 512 granules per 32x128 chunk, 1/thread ----
  const int sr   = tid >> 4;            // row 0..31
  const int slot = tid & 15;            // LDS granule slot 0..15
  const int sg   = (slot & 8) | ((slot & 7) ^ (sr & 7));   // src granule
  const uint16_t* xsrc = xb + (size_t)(m0 + sr) * F_DIM + sg * 8;
  uint16_t* const ldst0 = X0 + tid * 8; // granule G=tid, 16B each
  uint16_t* const ldst1 = X1 + tid * 8;

  // A fragment pointers: wave covers cols wid*32 .. wid*32+31
  const uint16_t* Apt[2];
  #pragma unroll
  for (int j = 0; j < 2; ++j)
    Apt[j] = Ab + (size_t)(wid * 32 + j * 16 + cl) * F_DIM + quad * 8;

  const char* faB = (char*)S + cl * 256;      // fa row base (ping at S)
  const int   clx = cl & 7;

  v4f acc[2][2];
  #pragma unroll
  for (int i = 0; i < 2; i++)
    #pragma unroll
    for (int j = 0; j < 2; j++) acc[i][j] = (v4f){0.f, 0.f, 0.f, 0.f};

#define STAGE_X(dst_, kk) g2lds16(xsrc + (kk), dst_)

#define COMP_X(base_, kelem_) do {                                                        \
    _Pragma("unroll")                                                                     \
    for (int s = 0; s < 4; ++s) {                                                         \
      const int gk = s * 4 + quad;                                                        \
      const int sl = (gk & 8) | ((gk & 7) ^ clx);                                         \
      v8s fa0 = *(const v8s*)((base_) + sl * 16);                                         \
      v8s fa1 = *(const v8s*)((base_) + 4096 + sl * 16);                                  \
      v8s fb0 = *(const v8s*)(Apt[0] + (kelem_) + s * 32);                                \
      v8s fb1 = *(const v8s*)(Apt[1] + (kelem_) + s * 32);                                \
      acc[0][0] = __builtin_amdgcn_mfma_f32_16x16x32_bf16(fa0, fb0, acc[0][0], 0, 0, 0);  \
      acc[0][1] = __builtin_amdgcn_mfma_f32_16x16x32_bf16(fa0, fb1, acc[0][1], 0, 0, 0);  \
      acc[1][0] = __builtin_amdgcn_mfma_f32_16x16x32_bf16(fa1, fb0, acc[1][0], 0, 0, 0);  \
      acc[1][1] = __builtin_amdgcn_mfma_f32_16x16x32_bf16(fa1, fb1, acc[1][1], 0, 0, 0);  \
    }                                                                                     \
  } while (0)

  // rows 16 apart share the same swizzle (since (r+16)&7 == r&7):
  // fa0 at faB (rows 0..15 region: row cl -> byte cl*256), fa1 at +16 rows
  // X buffers: X0 at S (faB), X1 at S+8192B. Chunk row stride = 256B.

  STAGE_X(ldst0, 0);
  for (int k0 = 0; k0 < F_DIM; k0 += 256) {
    __syncthreads();                       // X0 (cols k0) staged
    STAGE_X(ldst1, k0 + 128);              // prefetch odd chunk
    COMP_X(faB, k0);
    __syncthreads();                       // X1 staged
    if (k0 + 256 < F_DIM) STAGE_X(ldst0, k0 + 256);
    COMP_X(faB + 8192, k0 + 128);
  }

  // ---- epilogue: coeff fold + bf16 pack via LDS bounce ----
  __syncthreads();                         // done reading X1
  uint16_t* tile = S;                      // 32 x 264 bf16 = 16896 B
  #pragma unroll
  for (int mi = 0; mi < 2; ++mi)
    #pragma unroll
    for (int ni = 0; ni < 2; ++ni) {
      const int col = wid * 32 + ni * 16 + cl;
      const int e   = wid * 2 + ni;        // (col>>4), wave-uniform
      #pragma unroll
      for (int reg = 0; reg < 4; ++reg) {
        const int tl = mi * 16 + quad * 4 + reg;
        tile[tl * 264 + col] = f2bf(acc[mi][ni][reg] * coeffL[tl * 17 + e]);
      }
    }
  __syncthreads();
  #pragma unroll
  for (int p = 0; p < 2; ++p) {
    const int f4  = p * 512 + tid;         // 0..1023
    const int row = f4 >> 5;               // 0..31
    const int c16 = f4 & 31;
    *(uint4*)&wb[(size_t)(m0 + row) * KDIM + c16 * 8] =
        *(uint4*)&tile[row * 264 + c16 * 8];
  }
#undef STAGE_X
#undef COMP_X
}

// ---------------------------------------------------------------------------
// K3: gemm_wb (R0-exact), 64x256 tile (acc[2][8]/wave), BK=64 (4 iters),
// XCD-swizzled, two-pass fp32 LDS-bounce epilogue with 1KB-contiguous stores.
// ---------------------------------------------------------------------------
__global__ __launch_bounds__(256) void gemm_wb(
    const uint16_t* __restrict__ wbuf, const uint16_t* __restrict__ Bb,
    float* __restrict__ out) {
  __shared__ uint16_t S[20480];   // 40 KB: Ws 8 KB + Bs 32 KB
  uint16_t* Ws = S;               // 64 rows x 8 granules
  uint16_t* Bs = S + 4096;        // 256 rows x 8 granules
  const int tid  = threadIdx.x;
  const int b    = blockIdx.x;                       // 1024 blocks
  const int m_idx = (b & 7) + ((b >> 6) << 3);       // 0..127
  const int n_idx = (b >> 3) & 7;                    // 0..7
  const int m0 = m_idx * 64;
  const int n0 = n_idx * 256;
  const int lane = tid & 63;
  const int wid  = tid >> 6;
  const int wm   = (wid >> 1) * 32;
  const int wn   = (wid & 1) * 128;
  const int quad = lane >> 4;
  const int cl   = lane & 15;

  const int GW0 = wid * 64 + lane;
  const int GW1 = GW0 + 256;
  const int wr0 = GW0 >> 3, wg0 = (GW0 & 7) ^ (wr0 & 7);
  const int wr1 = GW1 >> 3, wg1 = (GW1 & 7) ^ (wr1 & 7);
  const uint16_t* wsrc0 = wbuf + (size_t)(m0 + wr0) * KDIM + wg0 * 8;
  const uint16_t* wsrc1 = wbuf + (size_t)(m0 + wr1) * KDIM + wg1 * 8;

  const uint16_t* bsrc[8];
  #pragma unroll
  for (int p = 0; p < 8; ++p) {
    const int G = p * 256 + wid * 64 + lane;
    const int r = G >> 3, g = (G & 7) ^ (r & 7);
    bsrc[p] = Bb + (size_t)(n0 + r) * KDIM + g * 8;
  }

  v4f acc[2][8];
  #pragma unroll
  for (int i = 0; i < 2; i++)
    #pragma unroll
    for (int j = 0; j < 8; j++) acc[i][j] = (v4f){0.f, 0.f, 0.f, 0.f};

  const int ma0 = wm + cl, ma1 = wm + 16 + cl;

  #pragma unroll
  for (int k0 = 0; k0 < KDIM; k0 += 64) {
    __syncthreads();
    g2lds16(wsrc0 + k0, Ws + wid * 512);
    g2lds16(wsrc1 + k0, Ws + wid * 512 + 2048);
    #pragma unroll
    for (int p = 0; p < 8; ++p)
      g2lds16(bsrc[p] + k0, Bs + (p * 256 + wid * 64) * 8);
    __syncthreads();
    #pragma unroll
    for (int ks = 0; ks < 2; ++ks) {
      const int gk = ks * 4 + quad;
      v8s fa0 = *(v8s*)&Ws[(ma0 * 8 + (gk ^ (ma0 & 7))) * 8];
      v8s fa1 = *(v8s*)&Ws[(ma1 * 8 + (gk ^ (ma1 & 7))) * 8];
      v8s fb[8];
      #pragma unroll
      for (int j = 0; j < 8; ++j) {
        const int nb = wn + j * 16 + cl;
        fb[j] = *(v8s*)&Bs[(nb * 8 + (gk ^ (nb & 7))) * 8];
      }
      #pragma unroll
      for (int j = 0; j < 8; ++j) {
        acc[0][j] = __builtin_amdgcn_mfma_f32_16x16x32_bf16(fa0, fb[j], acc[0][j], 0, 0, 0);
        acc[1][j] = __builtin_amdgcn_mfma_f32_16x16x32_bf16(fa1, fb[j], acc[1][j], 0, 0, 0);
      }
    }
  }

  float* ft = (float*)S;   // 32 x 260 floats
  #pragma unroll
  for (int h = 0; h < 2; ++h) {
    __syncthreads();
    if ((wid >> 1) == h) {
      #pragma unroll
      for (int mi = 0; mi < 2; mi++)
        #pragma unroll
        for (int j = 0; j < 8; j++) {
          const int col = wn + j * 16 + cl;
          #pragma unroll
          for (int reg = 0; reg < 4; reg++) {
            const int rl = mi * 16 + quad * 4 + reg;
            ft[rl * 260 + col] = acc[mi][j][reg];
          }
        }
    }
    __syncthreads();
    #pragma unroll
    for (int p = 0; p < 8; ++p) {
      const int f4  = p * 256 + tid;
      const int row = f4 >> 6;
      const int c4  = f4 & 63;
      float4 v = *(float4*)&ft[row * 260 + c4 * 4];
      *(float4*)&out[(size_t)(m0 + h * 32 + row) * O_DIM + n0 + c4 * 4] = v;
    }
  }
}

extern "C" void kernel_launch(void* const* d_in, const int* in_sizes, int n_in,
                              void* d_out, int out_size, void* d_ws, size_t ws_size,
                              hipStream_t stream) {
  (void)in_sizes; (void)n_in; (void)out_size; (void)ws_size;
  const float* x       = (const float*)d_in[0];
  const float* P       = (const float*)d_in[1];
  const float* A       = (const float*)d_in[2];
  const float* Bst     = (const float*)d_in[3];
  const float* scaling = (const float*)d_in[4];
  const int*   topk    = (const int*)d_in[5];
  float* out = (float*)d_out;

  char* ws = (char*)d_ws;
  uint16_t* xb     = (uint16_t*)(ws);                 // 33,554,432 B
  uint16_t* Ab     = (uint16_t*)(ws + 33554432);      //  1,048,576 B
  uint16_t* Bb     = (uint16_t*)(ws + 34603008);      //  1,048,576 B
  uint16_t* wbuf   = (uint16_t*)(ws + 35651584);      //  4,194,304 B
  float4*   parts  = (float4*)  (ws + 39845888);      //  4,194,304 B (no alias)

  hipLaunchKernelGGL(prep_weights, dim3(2048), dim3(256), 0, stream, A, Bst, Ab, Bb);
  hipLaunchKernelGGL(route_stream, dim3(8, 256), dim3(256), 0, stream, x, P, xb, parts);
  hipLaunchKernelGGL(gemm_xa, dim3(256), dim3(512), 0, stream,
                     xb, Ab, parts, scaling, topk, wbuf);
  hipLaunchKernelGGL(gemm_wb, dim3(1024), dim3(256), 0, stream, wbuf, Bb, out);
}

// Round 6
// 163.663 us; speedup vs baseline: 1.1239x; 1.1239x over previous
//
#include <hip/hip_runtime.h>
#include <hip/hip_bf16.h>
#include <stdint.h>

#define T_TOKENS 8192
#define F_DIM    2048
#define E_EXP    16
#define R_RANK   16
#define O_DIM    2048
#define KDIM     (E_EXP * R_RANK)   // 256

typedef short v8s __attribute__((ext_vector_type(8)));
typedef float v4f __attribute__((ext_vector_type(4)));

#define AS1 __attribute__((address_space(1)))
#define AS3 __attribute__((address_space(3)))

__device__ __forceinline__ uint16_t f2bf(float f) {
  uint32_t u = __builtin_bit_cast(uint32_t, f);
  u += 0x7fffu + ((u >> 16) & 1u);   // round-to-nearest-even
  return (uint16_t)(u >> 16);
}

// async global->LDS, 16B per lane; LDS dest = wave-uniform base + lane*16
__device__ __forceinline__ void g2lds16(const void* g, void* l) {
  __builtin_amdgcn_global_load_lds((const AS1 void*)g, (AS3 void*)l, 16, 0, 0);
}

// ---------------------------------------------------------------------------
// K1: route_stream (R4 shape) + weight-prep folded in as grid-x chunk c==8.
// Route: 2048 blocks (8/CU), 32 tokens x 256 cols per block, 1 thread =
// 1 token x 32 cols. Partials layout: float4 partials4[(c*4+e4)*8192 + t].
// Prep: 256 blocks interleaved 1-per-8 in dispatch order (x fastest) so the
// A/B cast+transpose hides inside the route dispatch (R1's y-APPENDED fold
// tailed the kernel and cost +6 us; x-interleave avoids the tail).
// ---------------------------------------------------------------------------
__global__ __launch_bounds__(256) void route_stream(
    const float* __restrict__ x, const float* __restrict__ P,
    const float* __restrict__ A, const float* __restrict__ Bst,
    uint16_t* __restrict__ xb, float4* __restrict__ partials4,
    uint16_t* __restrict__ Ab, uint16_t* __restrict__ Bb) {
  __shared__ float ps[16 * 256];   // 16 KB, linear (g2lds dest)
  const int tid = threadIdx.x;
  const int c   = blockIdx.x;      // 0..7 route chunk; 8 = weight prep
  const int by  = blockIdx.y;      // 0..255

  if (c == 8) {
    // ---- weight prep: this block owns elems [by*2048, (by+1)*2048) ----
    const int base = by * 2048;
    #pragma unroll
    for (int p = 0; p < 8; ++p) {
      const int i = base + p * 256 + tid;
      Ab[i] = f2bf(A[i]);
      const int k = i & (KDIM - 1);
      const int o = i >> 8;
      Bb[i] = f2bf(Bst[((size_t)(k >> 4) * O_DIM + o) * R_RANK + (k & 15)]);
    }
    return;
  }

  const int f0 = c * 256;
  #pragma unroll
  for (int p = 0; p < 4; ++p) {
    const int G = p * 256 + tid;                  // 0..1023
    g2lds16(&P[(size_t)(G >> 6) * F_DIM + f0 + (G & 63) * 4],
            (char*)ps + (p * 256 + (tid >> 6) * 64) * 16);
  }
  __syncthreads();

  const int sub = tid & 7;         // 32-col slice: cols {sub*4 + k*32}
  const int tg  = tid >> 3;        // 0..31 token within block
  const int row = by * 32 + tg;
  const float* xr = x  + (size_t)row * F_DIM + f0;
  uint16_t*    xw = xb + (size_t)row * F_DIM + f0;

  float a[16];
  #pragma unroll
  for (int e = 0; e < 16; ++e) a[e] = 0.f;

  float4 v[8];
  #pragma unroll
  for (int k = 0; k < 8; ++k)
    v[k] = *(const float4*)&xr[sub * 4 + k * 32];

  #pragma unroll
  for (int k = 0; k < 8; ++k) {
    uint2 pk;
    pk.x = (uint32_t)f2bf(v[k].x) | ((uint32_t)f2bf(v[k].y) << 16);
    pk.y = (uint32_t)f2bf(v[k].z) | ((uint32_t)f2bf(v[k].w) << 16);
    *(uint2*)&xw[sub * 4 + k * 32] = pk;
  }

  #pragma unroll
  for (int k = 0; k < 8; ++k) {
    const int col = sub * 4 + k * 32;
    #pragma unroll
    for (int e = 0; e < 16; ++e) {
      float4 pv = *(float4*)&ps[e * 256 + col];
      a[e] += v[k].x * pv.x; a[e] += v[k].y * pv.y;
      a[e] += v[k].z * pv.z; a[e] += v[k].w * pv.w;
    }
  }

  #pragma unroll
  for (int m = 1; m <= 4; m <<= 1) {
    #pragma unroll
    for (int e = 0; e < 16; ++e)
      a[e] += __shfl_xor(a[e], m, 64);
  }

  if (sub < 4) {
    partials4[((size_t)c * 4 + sub) * T_TOKENS + row] =
        make_float4(a[sub * 4], a[sub * 4 + 1], a[sub * 4 + 2], a[sub * 4 + 3]);
  }
}

// ---------------------------------------------------------------------------
// K2: gemm_xa (R0/R4-exact), 64x64 tile BK=128, XCD-swizzled linear grid,
// topk folded into prologue (tid<64: fp64 cross-chunk sum + topk + softmax).
// 512 blocks = 2 blocks/CU (cross-block overlap covers barrier drains).
// ---------------------------------------------------------------------------
__global__ __launch_bounds__(256) void gemm_xa(
    const uint16_t* __restrict__ xb, const uint16_t* __restrict__ Ab,
    const float4* __restrict__ partials4, const float* __restrict__ scaling,
    const int* __restrict__ topk, uint16_t* __restrict__ wb) {
  __shared__ uint16_t S[16384];   // 32 KB staging
  __shared__ float coeffL[64 * 17];
  uint16_t* Xh[2] = { S,         S + 4096  };
  uint16_t* Ah[2] = { S + 8192,  S + 12288 };
  const int tid  = threadIdx.x;
  const int b    = blockIdx.x;                       // 512 blocks
  const int m_idx = (b & 7) + ((b >> 5) << 3);       // 0..127 (same-XCD share m)
  const int n_idx = (b >> 3) & 3;                    // 0..3
  const int m0 = m_idx * 64, n0 = n_idx * 64;
  const int lane = tid & 63;
  const int wid  = tid >> 6;
  const int wm   = (wid >> 1) * 32;
  const int wn   = (wid & 1) * 32;
  const int quad = lane >> 4;
  const int cl   = lane & 15;

  // ---- routing prologue: tokens m0..m0+63 ----
  if (tid < 64) {
    const int t = m0 + tid;
    double s[16];
    #pragma unroll
    for (int e = 0; e < 16; ++e) s[e] = 0.0;
    for (int c = 0; c < 8; ++c) {
      #pragma unroll
      for (int e4 = 0; e4 < 4; ++e4) {
        float4 p = partials4[((size_t)c * 4 + e4) * T_TOKENS + t];
        s[e4 * 4]     += (double)p.x;
        s[e4 * 4 + 1] += (double)p.y;
        s[e4 * 4 + 2] += (double)p.z;
        s[e4 * 4 + 3] += (double)p.w;
      }
    }
    double v[16];
    #pragma unroll
    for (int e = 0; e < 16; ++e) v[e] = fabs(s[e]);
    int k = topk[0];
    if (k > 16) k = 16;
    if (k < 1)  k = 1;
    unsigned mask = 0;
    double mx = 0.0;
    float ssum = 0.f;
    for (int i = 0; i < k; ++i) {
      double bv = -1.0; int bj = 0;
      #pragma unroll
      for (int j = 0; j < 16; ++j) {
        bool ok = !((mask >> j) & 1u) && (v[j] > bv);
        bv = ok ? v[j] : bv;
        bj = ok ? j  : bj;
      }
      mask |= 1u << bj;
      if (i == 0) mx = bv;
      ssum += expf((float)(bv - mx));
    }
    const float sc = scaling[0];
    #pragma unroll
    for (int j = 0; j < 16; ++j)
      coeffL[tid * 17 + j] = ((mask >> j) & 1u)
          ? expf((float)(v[j] - mx)) / ssum * sc : 0.f;
  }

  // ---- GEMM ----
  const int G0 = wid * 64 + lane;
  const int G1 = G0 + 256;
  const int r0 = G0 >> 3, g0 = (G0 & 7) ^ (r0 & 7);
  const int r1 = G1 >> 3, g1 = (G1 & 7) ^ (r1 & 7);
  const uint16_t* xs0 = xb + (size_t)(m0 + r0) * F_DIM + g0 * 8;
  const uint16_t* xs1 = xb + (size_t)(m0 + r1) * F_DIM + g1 * 8;
  const uint16_t* as0 = Ab + (size_t)(n0 + r0) * F_DIM + g0 * 8;
  const uint16_t* as1 = Ab + (size_t)(n0 + r1) * F_DIM + g1 * 8;
  const int d0 = wid * 512;
  const int d1 = wid * 512 + 2048;

  const int ma0 = wm + cl, ma1 = wm + 16 + cl;
  const int nb0 = wn + cl, nb1 = wn + 16 + cl;

  v4f acc[2][2];
  #pragma unroll
  for (int i = 0; i < 2; i++)
    #pragma unroll
    for (int j = 0; j < 2; j++) acc[i][j] = (v4f){0.f, 0.f, 0.f, 0.f};

  for (int k0 = 0; k0 < F_DIM; k0 += 128) {
    __syncthreads();
    g2lds16(xs0 + k0,      Xh[0] + d0);
    g2lds16(xs1 + k0,      Xh[0] + d1);
    g2lds16(as0 + k0,      Ah[0] + d0);
    g2lds16(as1 + k0,      Ah[0] + d1);
    g2lds16(xs0 + k0 + 64, Xh[1] + d0);
    g2lds16(xs1 + k0 + 64, Xh[1] + d1);
    g2lds16(as0 + k0 + 64, Ah[1] + d0);
    g2lds16(as1 + k0 + 64, Ah[1] + d1);
    __syncthreads();
    #pragma unroll
    for (int h = 0; h < 2; ++h) {
      #pragma unroll
      for (int ks = 0; ks < 2; ++ks) {
        const int gk = ks * 4 + quad;
        v8s fa0 = *(v8s*)&Xh[h][(ma0 * 8 + (gk ^ (ma0 & 7))) * 8];
        v8s fa1 = *(v8s*)&Xh[h][(ma1 * 8 + (gk ^ (ma1 & 7))) * 8];
        v8s fb0 = *(v8s*)&Ah[h][(nb0 * 8 + (gk ^ (nb0 & 7))) * 8];
        v8s fb1 = *(v8s*)&Ah[h][(nb1 * 8 + (gk ^ (nb1 & 7))) * 8];
        acc[0][0] = __builtin_amdgcn_mfma_f32_16x16x32_bf16(fa0, fb0, acc[0][0], 0, 0, 0);
        acc[0][1] = __builtin_amdgcn_mfma_f32_16x16x32_bf16(fa0, fb1, acc[0][1], 0, 0, 0);
        acc[1][0] = __builtin_amdgcn_mfma_f32_16x16x32_bf16(fa1, fb0, acc[1][0], 0, 0, 0);
        acc[1][1] = __builtin_amdgcn_mfma_f32_16x16x32_bf16(fa1, fb1, acc[1][1], 0, 0, 0);
      }
    }
  }

  // epilogue: coeff fold + bf16 pack via LDS bounce, 128B-contiguous stores
  __syncthreads();
  uint16_t* tile = S;   // stride 72
  #pragma unroll
  for (int mi = 0; mi < 2; mi++)
    #pragma unroll
    for (int ni = 0; ni < 2; ni++) {
      const int nl = wn + ni * 16 + cl;
      const int eidx = (n0 + nl) >> 4;
      #pragma unroll
      for (int reg = 0; reg < 4; reg++) {
        const int tl = wm + mi * 16 + quad * 4 + reg;
        float wv = acc[mi][ni][reg] * coeffL[tl * 17 + eidx];
        tile[tl * 72 + nl] = f2bf(wv);
      }
    }
  __syncthreads();
  #pragma unroll
  for (int p = 0; p < 2; ++p) {
    const int row  = p * 32 + (tid >> 3);
    const int colg = (tid & 7) * 8;
    uint4 val = *(uint4*)&tile[row * 72 + colg];
    *(uint4*)&wb[(size_t)(m0 + row) * KDIM + n0 + colg] = val;
  }
}

// ---------------------------------------------------------------------------
// K3: gemm_wb (R0/R4-exact), 64x256 tile (acc[2][8]/wave), BK=64 (4 iters),
// XCD-swizzled, two-pass fp32 LDS-bounce epilogue with 1KB-contiguous stores.
// ---------------------------------------------------------------------------
__global__ __launch_bounds__(256) void gemm_wb(
    const uint16_t* __restrict__ wbuf, const uint16_t* __restrict__ Bb,
    float* __restrict__ out) {
  __shared__ uint16_t S[20480];   // 40 KB: Ws 8 KB + Bs 32 KB
  uint16_t* Ws = S;               // 64 rows x 8 granules
  uint16_t* Bs = S + 4096;        // 256 rows x 8 granules
  const int tid  = threadIdx.x;
  const int b    = blockIdx.x;                       // 1024 blocks
  const int m_idx = (b & 7) + ((b >> 6) << 3);       // 0..127
  const int n_idx = (b >> 3) & 7;                    // 0..7
  const int m0 = m_idx * 64;
  const int n0 = n_idx * 256;
  const int lane = tid & 63;
  const int wid  = tid >> 6;
  const int wm   = (wid >> 1) * 32;
  const int wn   = (wid & 1) * 128;
  const int quad = lane >> 4;
  const int cl   = lane & 15;

  const int GW0 = wid * 64 + lane;
  const int GW1 = GW0 + 256;
  const int wr0 = GW0 >> 3, wg0 = (GW0 & 7) ^ (wr0 & 7);
  const int wr1 = GW1 >> 3, wg1 = (GW1 & 7) ^ (wr1 & 7);
  const uint16_t* wsrc0 = wbuf + (size_t)(m0 + wr0) * KDIM + wg0 * 8;
  const uint16_t* wsrc1 = wbuf + (size_t)(m0 + wr1) * KDIM + wg1 * 8;

  const uint16_t* bsrc[8];
  #pragma unroll
  for (int p = 0; p < 8; ++p) {
    const int G = p * 256 + wid * 64 + lane;
    const int r = G >> 3, g = (G & 7) ^ (r & 7);
    bsrc[p] = Bb + (size_t)(n0 + r) * KDIM + g * 8;
  }

  v4f acc[2][8];
  #pragma unroll
  for (int i = 0; i < 2; i++)
    #pragma unroll
    for (int j = 0; j < 8; j++) acc[i][j] = (v4f){0.f, 0.f, 0.f, 0.f};

  const int ma0 = wm + cl, ma1 = wm + 16 + cl;

  #pragma unroll
  for (int k0 = 0; k0 < KDIM; k0 += 64) {
    __syncthreads();
    g2lds16(wsrc0 + k0, Ws + wid * 512);
    g2lds16(wsrc1 + k0, Ws + wid * 512 + 2048);
    #pragma unroll
    for (int p = 0; p < 8; ++p)
      g2lds16(bsrc[p] + k0, Bs + (p * 256 + wid * 64) * 8);
    __syncthreads();
    #pragma unroll
    for (int ks = 0; ks < 2; ++ks) {
      const int gk = ks * 4 + quad;
      v8s fa0 = *(v8s*)&Ws[(ma0 * 8 + (gk ^ (ma0 & 7))) * 8];
      v8s fa1 = *(v8s*)&Ws[(ma1 * 8 + (gk ^ (ma1 & 7))) * 8];
      v8s fb[8];
      #pragma unroll
      for (int j = 0; j < 8; ++j) {
        const int nb = wn + j * 16 + cl;
        fb[j] = *(v8s*)&Bs[(nb * 8 + (gk ^ (nb & 7))) * 8];
      }
      #pragma unroll
      for (int j = 0; j < 8; ++j) {
        acc[0][j] = __builtin_amdgcn_mfma_f32_16x16x32_bf16(fa0, fb[j], acc[0][j], 0, 0, 0);
        acc[1][j] = __builtin_amdgcn_mfma_f32_16x16x32_bf16(fa1, fb[j], acc[1][j], 0, 0, 0);
      }
    }
  }

  float* ft = (float*)S;   // 32 x 260 floats
  #pragma unroll
  for (int h = 0; h < 2; ++h) {
    __syncthreads();
    if ((wid >> 1) == h) {
      #pragma unroll
      for (int mi = 0; mi < 2; mi++)
        #pragma unroll
        for (int j = 0; j < 8; j++) {
          const int col = wn + j * 16 + cl;
          #pragma unroll
          for (int reg = 0; reg < 4; reg++) {
            const int rl = mi * 16 + quad * 4 + reg;
            ft[rl * 260 + col] = acc[mi][j][reg];
          }
        }
    }
    __syncthreads();
    #pragma unroll
    for (int p = 0; p < 8; ++p) {
      const int f4  = p * 256 + tid;
      const int row = f4 >> 6;
      const int c4  = f4 & 63;
      float4 v = *(float4*)&ft[row * 260 + c4 * 4];
      *(float4*)&out[(size_t)(m0 + h * 32 + row) * O_DIM + n0 + c4 * 4] = v;
    }
  }
}

extern "C" void kernel_launch(void* const* d_in, const int* in_sizes, int n_in,
                              void* d_out, int out_size, void* d_ws, size_t ws_size,
                              hipStream_t stream) {
  (void)in_sizes; (void)n_in; (void)out_size; (void)ws_size;
  const float* x       = (const float*)d_in[0];
  const float* P       = (const float*)d_in[1];
  const float* A       = (const float*)d_in[2];
  const float* Bst     = (const float*)d_in[3];
  const float* scaling = (const float*)d_in[4];
  const int*   topk    = (const int*)d_in[5];
  float* out = (float*)d_out;

  char* ws = (char*)d_ws;
  uint16_t* xb     = (uint16_t*)(ws);                 // 33,554,432 B
  uint16_t* Ab     = (uint16_t*)(ws + 33554432);      //  1,048,576 B
  uint16_t* Bb     = (uint16_t*)(ws + 34603008);      //  1,048,576 B
  uint16_t* wbuf   = (uint16_t*)(ws + 35651584);      //  4,194,304 B
  float4*   parts  = (float4*)  (ws + 39845888);      //  4,194,304 B (no alias)

  // grid.x: 0..7 = route chunks, 8 = weight prep (x-interleaved in dispatch)
  hipLaunchKernelGGL(route_stream, dim3(9, 256), dim3(256), 0, stream,
                     x, P, A, Bst, xb, parts, Ab, Bb);
  hipLaunchKernelGGL(gemm_xa, dim3(512), dim3(256), 0, stream,
                     xb, Ab, parts, scaling, topk, wbuf);
  hipLaunchKernelGGL(gemm_wb, dim3(1024), dim3(256), 0, stream, wbuf, Bb, out);
}

// Round 7
// 163.247 us; speedup vs baseline: 1.1268x; 1.0026x over previous
//
#include <hip/hip_runtime.h>
#include <hip/hip_bf16.h>
#include <stdint.h>

#define T_TOKENS 8192
#define F_DIM    2048
#define E_EXP    16
#define R_RANK   16
#define O_DIM    2048
#define KDIM     (E_EXP * R_RANK)   // 256

typedef short v8s __attribute__((ext_vector_type(8)));
typedef float v4f __attribute__((ext_vector_type(4)));

#define AS1 __attribute__((address_space(1)))
#define AS3 __attribute__((address_space(3)))

__device__ __forceinline__ uint16_t f2bf(float f) {
  uint32_t u = __builtin_bit_cast(uint32_t, f);
  u += 0x7fffu + ((u >> 16) & 1u);   // round-to-nearest-even
  return (uint16_t)(u >> 16);
}

// async global->LDS, 16B per lane; LDS dest = wave-uniform base + lane*16
__device__ __forceinline__ void g2lds16(const void* g, void* l) {
  __builtin_amdgcn_global_load_lds((const AS1 void*)g, (AS3 void*)l, 16, 0, 0);
}

// ---------------------------------------------------------------------------
// K1: route_stream v3 — 2-token register tiling. Grid 9 x 128:
//   c in 0..7: route chunk (256 cols), 64 tokens/block, 256 threads.
//     Thread = 2 tokens x 32 cols (t0 = by*64+tg, t1 = t0+32). One P ds_read
//     feeds 8 FMAs (was 4) -> LDS read volume halves; P staging traffic
//     halves (1024 blocks x 16 KB). Per-token math bit-identical to R4/R6.
//   c == 8: weight prep, 128 blocks x 4096 elems (x-interleaved in dispatch).
// Partials layout: float4 partials4[(c*4+e4)*8192 + t].
// ---------------------------------------------------------------------------
__global__ __launch_bounds__(256) void route_stream(
    const float* __restrict__ x, const float* __restrict__ P,
    const float* __restrict__ A, const float* __restrict__ Bst,
    uint16_t* __restrict__ xb, float4* __restrict__ partials4,
    uint16_t* __restrict__ Ab, uint16_t* __restrict__ Bb) {
  __shared__ float ps[16 * 256];   // 16 KB, linear (g2lds dest)
  const int tid = threadIdx.x;
  const int c   = blockIdx.x;      // 0..7 route chunk; 8 = weight prep
  const int by  = blockIdx.y;      // 0..127

  if (c == 8) {
    // ---- weight prep: this block owns elems [by*4096, (by+1)*4096) ----
    const int base = by * 4096;
    #pragma unroll
    for (int p = 0; p < 16; ++p) {
      const int i = base + p * 256 + tid;
      Ab[i] = f2bf(A[i]);
      const int k = i & (KDIM - 1);
      const int o = i >> 8;
      Bb[i] = f2bf(Bst[((size_t)(k >> 4) * O_DIM + o) * R_RANK + (k & 15)]);
    }
    return;
  }

  const int f0 = c * 256;
  #pragma unroll
  for (int p = 0; p < 4; ++p) {
    const int G = p * 256 + tid;                  // 0..1023
    g2lds16(&P[(size_t)(G >> 6) * F_DIM + f0 + (G & 63) * 4],
            (char*)ps + (p * 256 + (tid >> 6) * 64) * 16);
  }
  __syncthreads();

  const int sub = tid & 7;         // 32-col slice: cols {sub*4 + k*32}
  const int tg  = tid >> 3;        // 0..31
  const int r0  = by * 64 + tg;    // token A
  const int r1  = r0 + 32;         // token B
  const float* xr0 = x  + (size_t)r0 * F_DIM + f0;
  const float* xr1 = x  + (size_t)r1 * F_DIM + f0;
  uint16_t*    xw0 = xb + (size_t)r0 * F_DIM + f0;
  uint16_t*    xw1 = xb + (size_t)r1 * F_DIM + f0;

  float a0[16], a1[16];
  #pragma unroll
  for (int e = 0; e < 16; ++e) { a0[e] = 0.f; a1[e] = 0.f; }

  // load both tokens' slices up-front (16 outstanding loads / thread)
  float4 v0[8], v1[8];
  #pragma unroll
  for (int k = 0; k < 8; ++k)
    v0[k] = *(const float4*)&xr0[sub * 4 + k * 32];
  #pragma unroll
  for (int k = 0; k < 8; ++k)
    v1[k] = *(const float4*)&xr1[sub * 4 + k * 32];

  // pack + store bf16 (both tokens)
  #pragma unroll
  for (int k = 0; k < 8; ++k) {
    uint2 pk0, pk1;
    pk0.x = (uint32_t)f2bf(v0[k].x) | ((uint32_t)f2bf(v0[k].y) << 16);
    pk0.y = (uint32_t)f2bf(v0[k].z) | ((uint32_t)f2bf(v0[k].w) << 16);
    pk1.x = (uint32_t)f2bf(v1[k].x) | ((uint32_t)f2bf(v1[k].y) << 16);
    pk1.y = (uint32_t)f2bf(v1[k].z) | ((uint32_t)f2bf(v1[k].w) << 16);
    *(uint2*)&xw0[sub * 4 + k * 32] = pk0;
    *(uint2*)&xw1[sub * 4 + k * 32] = pk1;
  }

  // sims FMA: one ds_read_b128 serves both tokens (8 FMAs / read)
  #pragma unroll
  for (int k = 0; k < 8; ++k) {
    const int col = sub * 4 + k * 32;
    #pragma unroll
    for (int e = 0; e < 16; ++e) {
      float4 pv = *(float4*)&ps[e * 256 + col];
      a0[e] += v0[k].x * pv.x; a0[e] += v0[k].y * pv.y;
      a0[e] += v0[k].z * pv.z; a0[e] += v0[k].w * pv.w;
      a1[e] += v1[k].x * pv.x; a1[e] += v1[k].y * pv.y;
      a1[e] += v1[k].z * pv.z; a1[e] += v1[k].w * pv.w;
    }
  }

  // reduce across the 8 sub-lanes: 3 butterfly rounds per token
  #pragma unroll
  for (int m = 1; m <= 4; m <<= 1) {
    #pragma unroll
    for (int e = 0; e < 16; ++e) {
      a0[e] += __shfl_xor(a0[e], m, 64);
      a1[e] += __shfl_xor(a1[e], m, 64);
    }
  }

  if (sub < 4) {
    partials4[((size_t)c * 4 + sub) * T_TOKENS + r0] =
        make_float4(a0[sub * 4], a0[sub * 4 + 1], a0[sub * 4 + 2], a0[sub * 4 + 3]);
    partials4[((size_t)c * 4 + sub) * T_TOKENS + r1] =
        make_float4(a1[sub * 4], a1[sub * 4 + 1], a1[sub * 4 + 2], a1[sub * 4 + 3]);
  }
}

// ---------------------------------------------------------------------------
// K2: gemm_xa (R0/R4-exact), 64x64 tile BK=128, XCD-swizzled linear grid,
// topk folded into prologue (tid<64: fp64 cross-chunk sum + topk + softmax).
// 512 blocks = 2 blocks/CU (cross-block overlap covers barrier drains).
// ---------------------------------------------------------------------------
__global__ __launch_bounds__(256) void gemm_xa(
    const uint16_t* __restrict__ xb, const uint16_t* __restrict__ Ab,
    const float4* __restrict__ partials4, const float* __restrict__ scaling,
    const int* __restrict__ topk, uint16_t* __restrict__ wb) {
  __shared__ uint16_t S[16384];   // 32 KB staging
  __shared__ float coeffL[64 * 17];
  uint16_t* Xh[2] = { S,         S + 4096  };
  uint16_t* Ah[2] = { S + 8192,  S + 12288 };
  const int tid  = threadIdx.x;
  const int b    = blockIdx.x;                       // 512 blocks
  const int m_idx = (b & 7) + ((b >> 5) << 3);       // 0..127 (same-XCD share m)
  const int n_idx = (b >> 3) & 3;                    // 0..3
  const int m0 = m_idx * 64, n0 = n_idx * 64;
  const int lane = tid & 63;
  const int wid  = tid >> 6;
  const int wm   = (wid >> 1) * 32;
  const int wn   = (wid & 1) * 32;
  const int quad = lane >> 4;
  const int cl   = lane & 15;

  // ---- routing prologue: tokens m0..m0+63 ----
  if (tid < 64) {
    const int t = m0 + tid;
    double s[16];
    #pragma unroll
    for (int e = 0; e < 16; ++e) s[e] = 0.0;
    for (int c = 0; c < 8; ++c) {
      #pragma unroll
      for (int e4 = 0; e4 < 4; ++e4) {
        float4 p = partials4[((size_t)c * 4 + e4) * T_TOKENS + t];
        s[e4 * 4]     += (double)p.x;
        s[e4 * 4 + 1] += (double)p.y;
        s[e4 * 4 + 2] += (double)p.z;
        s[e4 * 4 + 3] += (double)p.w;
      }
    }
    double v[16];
    #pragma unroll
    for (int e = 0; e < 16; ++e) v[e] = fabs(s[e]);
    int k = topk[0];
    if (k > 16) k = 16;
    if (k < 1)  k = 1;
    unsigned mask = 0;
    double mx = 0.0;
    float ssum = 0.f;
    for (int i = 0; i < k; ++i) {
      double bv = -1.0; int bj = 0;
      #pragma unroll
      for (int j = 0; j < 16; ++j) {
        bool ok = !((mask >> j) & 1u) && (v[j] > bv);
        bv = ok ? v[j] : bv;
        bj = ok ? j  : bj;
      }
      mask |= 1u << bj;
      if (i == 0) mx = bv;
      ssum += expf((float)(bv - mx));
    }
    const float sc = scaling[0];
    #pragma unroll
    for (int j = 0; j < 16; ++j)
      coeffL[tid * 17 + j] = ((mask >> j) & 1u)
          ? expf((float)(v[j] - mx)) / ssum * sc : 0.f;
  }

  // ---- GEMM ----
  const int G0 = wid * 64 + lane;
  const int G1 = G0 + 256;
  const int r0 = G0 >> 3, g0 = (G0 & 7) ^ (r0 & 7);
  const int r1 = G1 >> 3, g1 = (G1 & 7) ^ (r1 & 7);
  const uint16_t* xs0 = xb + (size_t)(m0 + r0) * F_DIM + g0 * 8;
  const uint16_t* xs1 = xb + (size_t)(m0 + r1) * F_DIM + g1 * 8;
  const uint16_t* as0 = Ab + (size_t)(n0 + r0) * F_DIM + g0 * 8;
  const uint16_t* as1 = Ab + (size_t)(n0 + r1) * F_DIM + g1 * 8;
  const int d0 = wid * 512;
  const int d1 = wid * 512 + 2048;

  const int ma0 = wm + cl, ma1 = wm + 16 + cl;
  const int nb0 = wn + cl, nb1 = wn + 16 + cl;

  v4f acc[2][2];
  #pragma unroll
  for (int i = 0; i < 2; i++)
    #pragma unroll
    for (int j = 0; j < 2; j++) acc[i][j] = (v4f){0.f, 0.f, 0.f, 0.f};

  for (int k0 = 0; k0 < F_DIM; k0 += 128) {
    __syncthreads();
    g2lds16(xs0 + k0,      Xh[0] + d0);
    g2lds16(xs1 + k0,      Xh[0] + d1);
    g2lds16(as0 + k0,      Ah[0] + d0);
    g2lds16(as1 + k0,      Ah[0] + d1);
    g2lds16(xs0 + k0 + 64, Xh[1] + d0);
    g2lds16(xs1 + k0 + 64, Xh[1] + d1);
    g2lds16(as0 + k0 + 64, Ah[1] + d0);
    g2lds16(as1 + k0 + 64, Ah[1] + d1);
    __syncthreads();
    #pragma unroll
    for (int h = 0; h < 2; ++h) {
      #pragma unroll
      for (int ks = 0; ks < 2; ++ks) {
        const int gk = ks * 4 + quad;
        v8s fa0 = *(v8s*)&Xh[h][(ma0 * 8 + (gk ^ (ma0 & 7))) * 8];
        v8s fa1 = *(v8s*)&Xh[h][(ma1 * 8 + (gk ^ (ma1 & 7))) * 8];
        v8s fb0 = *(v8s*)&Ah[h][(nb0 * 8 + (gk ^ (nb0 & 7))) * 8];
        v8s fb1 = *(v8s*)&Ah[h][(nb1 * 8 + (gk ^ (nb1 & 7))) * 8];
        acc[0][0] = __builtin_amdgcn_mfma_f32_16x16x32_bf16(fa0, fb0, acc[0][0], 0, 0, 0);
        acc[0][1] = __builtin_amdgcn_mfma_f32_16x16x32_bf16(fa0, fb1, acc[0][1], 0, 0, 0);
        acc[1][0] = __builtin_amdgcn_mfma_f32_16x16x32_bf16(fa1, fb0, acc[1][0], 0, 0, 0);
        acc[1][1] = __builtin_amdgcn_mfma_f32_16x16x32_bf16(fa1, fb1, acc[1][1], 0, 0, 0);
      }
    }
  }

  // epilogue: coeff fold + bf16 pack via LDS bounce, 128B-contiguous stores
  __syncthreads();
  uint16_t* tile = S;   // stride 72
  #pragma unroll
  for (int mi = 0; mi < 2; mi++)
    #pragma unroll
    for (int ni = 0; ni < 2; ni++) {
      const int nl = wn + ni * 16 + cl;
      const int eidx = (n0 + nl) >> 4;
      #pragma unroll
      for (int reg = 0; reg < 4; reg++) {
        const int tl = wm + mi * 16 + quad * 4 + reg;
        float wv = acc[mi][ni][reg] * coeffL[tl * 17 + eidx];
        tile[tl * 72 + nl] = f2bf(wv);
      }
    }
  __syncthreads();
  #pragma unroll
  for (int p = 0; p < 2; ++p) {
    const int row  = p * 32 + (tid >> 3);
    const int colg = (tid & 7) * 8;
    uint4 val = *(uint4*)&tile[row * 72 + colg];
    *(uint4*)&wb[(size_t)(m0 + row) * KDIM + n0 + colg] = val;
  }
}

// ---------------------------------------------------------------------------
// K3: gemm_wb (R0/R4-exact), 64x256 tile (acc[2][8]/wave), BK=64 (4 iters),
// XCD-swizzled, two-pass fp32 LDS-bounce epilogue with 1KB-contiguous stores.
// ---------------------------------------------------------------------------
__global__ __launch_bounds__(256) void gemm_wb(
    const uint16_t* __restrict__ wbuf, const uint16_t* __restrict__ Bb,
    float* __restrict__ out) {
  __shared__ uint16_t S[20480];   // 40 KB: Ws 8 KB + Bs 32 KB
  uint16_t* Ws = S;               // 64 rows x 8 granules
  uint16_t* Bs = S + 4096;        // 256 rows x 8 granules
  const int tid  = threadIdx.x;
  const int b    = blockIdx.x;                       // 1024 blocks
  const int m_idx = (b & 7) + ((b >> 6) << 3);       // 0..127
  const int n_idx = (b >> 3) & 7;                    // 0..7
  const int m0 = m_idx * 64;
  const int n0 = n_idx * 256;
  const int lane = tid & 63;
  const int wid  = tid >> 6;
  const int wm   = (wid >> 1) * 32;
  const int wn   = (wid & 1) * 128;
  const int quad = lane >> 4;
  const int cl   = lane & 15;

  const int GW0 = wid * 64 + lane;
  const int GW1 = GW0 + 256;
  const int wr0 = GW0 >> 3, wg0 = (GW0 & 7) ^ (wr0 & 7);
  const int wr1 = GW1 >> 3, wg1 = (GW1 & 7) ^ (wr1 & 7);
  const uint16_t* wsrc0 = wbuf + (size_t)(m0 + wr0) * KDIM + wg0 * 8;
  const uint16_t* wsrc1 = wbuf + (size_t)(m0 + wr1) * KDIM + wg1 * 8;

  const uint16_t* bsrc[8];
  #pragma unroll
  for (int p = 0; p < 8; ++p) {
    const int G = p * 256 + wid * 64 + lane;
    const int r = G >> 3, g = (G & 7) ^ (r & 7);
    bsrc[p] = Bb + (size_t)(n0 + r) * KDIM + g * 8;
  }

  v4f acc[2][8];
  #pragma unroll
  for (int i = 0; i < 2; i++)
    #pragma unroll
    for (int j = 0; j < 8; j++) acc[i][j] = (v4f){0.f, 0.f, 0.f, 0.f};

  const int ma0 = wm + cl, ma1 = wm + 16 + cl;

  #pragma unroll
  for (int k0 = 0; k0 < KDIM; k0 += 64) {
    __syncthreads();
    g2lds16(wsrc0 + k0, Ws + wid * 512);
    g2lds16(wsrc1 + k0, Ws + wid * 512 + 2048);
    #pragma unroll
    for (int p = 0; p < 8; ++p)
      g2lds16(bsrc[p] + k0, Bs + (p * 256 + wid * 64) * 8);
    __syncthreads();
    #pragma unroll
    for (int ks = 0; ks < 2; ++ks) {
      const int gk = ks * 4 + quad;
      v8s fa0 = *(v8s*)&Ws[(ma0 * 8 + (gk ^ (ma0 & 7))) * 8];
      v8s fa1 = *(v8s*)&Ws[(ma1 * 8 + (gk ^ (ma1 & 7))) * 8];
      v8s fb[8];
      #pragma unroll
      for (int j = 0; j < 8; ++j) {
        const int nb = wn + j * 16 + cl;
        fb[j] = *(v8s*)&Bs[(nb * 8 + (gk ^ (nb & 7))) * 8];
      }
      #pragma unroll
      for (int j = 0; j < 8; ++j) {
        acc[0][j] = __builtin_amdgcn_mfma_f32_16x16x32_bf16(fa0, fb[j], acc[0][j], 0, 0, 0);
        acc[1][j] = __builtin_amdgcn_mfma_f32_16x16x32_bf16(fa1, fb[j], acc[1][j], 0, 0, 0);
      }
    }
  }

  float* ft = (float*)S;   // 32 x 260 floats
  #pragma unroll
  for (int h = 0; h < 2; ++h) {
    __syncthreads();
    if ((wid >> 1) == h) {
      #pragma unroll
      for (int mi = 0; mi < 2; mi++)
        #pragma unroll
        for (int j = 0; j < 8; j++) {
          const int col = wn + j * 16 + cl;
          #pragma unroll
          for (int reg = 0; reg < 4; reg++) {
            const int rl = mi * 16 + quad * 4 + reg;
            ft[rl * 260 + col] = acc[mi][j][reg];
          }
        }
    }
    __syncthreads();
    #pragma unroll
    for (int p = 0; p < 8; ++p) {
      const int f4  = p * 256 + tid;
      const int row = f4 >> 6;
      const int c4  = f4 & 63;
      float4 v = *(float4*)&ft[row * 260 + c4 * 4];
      *(float4*)&out[(size_t)(m0 + h * 32 + row) * O_DIM + n0 + c4 * 4] = v;
    }
  }
}

extern "C" void kernel_launch(void* const* d_in, const int* in_sizes, int n_in,
                              void* d_out, int out_size, void* d_ws, size_t ws_size,
                              hipStream_t stream) {
  (void)in_sizes; (void)n_in; (void)out_size; (void)ws_size;
  const float* x       = (const float*)d_in[0];
  const float* P       = (const float*)d_in[1];
  const float* A       = (const float*)d_in[2];
  const float* Bst     = (const float*)d_in[3];
  const float* scaling = (const float*)d_in[4];
  const int*   topk    = (const int*)d_in[5];
  float* out = (float*)d_out;

  char* ws = (char*)d_ws;
  uint16_t* xb     = (uint16_t*)(ws);                 // 33,554,432 B
  uint16_t* Ab     = (uint16_t*)(ws + 33554432);      //  1,048,576 B
  uint16_t* Bb     = (uint16_t*)(ws + 34603008);      //  1,048,576 B
  uint16_t* wbuf   = (uint16_t*)(ws + 35651584);      //  4,194,304 B
  float4*   parts  = (float4*)  (ws + 39845888);      //  4,194,304 B (no alias)

  // grid.x: 0..7 = route chunks (64 tokens/block), 8 = weight prep
  hipLaunchKernelGGL(route_stream, dim3(9, 128), dim3(256), 0, stream,
                     x, P, A, Bst, xb, parts, Ab, Bb);
  hipLaunchKernelGGL(gemm_xa, dim3(512), dim3(256), 0, stream,
                     xb, Ab, parts, scaling, topk, wbuf);
  hipLaunchKernelGGL(gemm_wb, dim3(1024), dim3(256), 0, stream, wbuf, Bb, out);
}